// Round 1
// baseline (94.612 us; speedup 1.0000x reference)
//
#include <hip/hip_runtime.h>

typedef _Float16 f16;
typedef f16  f16x8 __attribute__((ext_vector_type(8)));
typedef float f32x4 __attribute__((ext_vector_type(4)));

#define K_DIM 512
#define BM 128
#define BN 128
#define BK 32
#define NT (K_DIM / BK)   /* 16 K-steps */

// ---------------------------------------------------------------------------
// Weight convert: Wq, Wo (fp32 [512][512]) -> fp16 copies in workspace
// ---------------------------------------------------------------------------
__global__ void convert_w_kernel(const float* __restrict__ wq,
                                 const float* __restrict__ wo,
                                 f16* __restrict__ wq_h,
                                 f16* __restrict__ wo_h) {
    int i = blockIdx.x * blockDim.x + threadIdx.x;   // each thread: one float4
    const int n4 = (512 * 512) / 4;                  // 65536 float4 per weight
    const float4* src;
    f16* dst;
    if (i < n4) { src = (const float4*)wq; dst = wq_h; }
    else        { src = (const float4*)wo; dst = wo_h; i -= n4; }
    float4 v = src[i];
    f16* p = dst + (size_t)i * 4;
    p[0] = (f16)v.x; p[1] = (f16)v.y; p[2] = (f16)v.z; p[3] = (f16)v.w;
}

// ---------------------------------------------------------------------------
// GEMM: C[M x 512] = A[M x 512] * B^T   (B stored [N=512][K=512] row-major)
//  CONV_A:  A is fp32, convert to fp16 while staging (GEMM1: A = x)
//  QUANTUM: epilogue = cumprod(cos(.)) over 8-wide groups along N, fp16 store
//           else plain fp32 store (GEMM2)
// 256 threads = 4 waves (2x2), wave tile 64x64, mfma_f32_16x16x32_f16
// ---------------------------------------------------------------------------
template <bool CONV_A, bool QUANTUM>
__global__ __launch_bounds__(256, 2)
void gemm_kernel(const void* __restrict__ Aptr,
                 const f16* __restrict__ B,
                 void* __restrict__ Cptr) {
    __shared__ f16 As[2][BM * BK];
    __shared__ f16 Bs[2][BN * BK];

    const int tid  = threadIdx.x;
    const int lane = tid & 63;
    const int wave = tid >> 6;
    const int wm = (wave >> 1) * 64;   // wave row offset in tile
    const int wn = (wave & 1) * 64;    // wave col offset in tile

    const int n0 = blockIdx.x * BN;
    const int m0 = blockIdx.y * BM;

    // staging: tile is 128 rows x 4 k-groups (8 elems each) = 512 groups,
    // 256 threads handle 2 groups each. group g: row = g>>2, k-off = (g&3)*8
    const int ar0 = tid >> 2,        ak0 = (tid & 3) * 8;
    const int ar1 = (tid + 256) >> 2, ak1 = ((tid + 256) & 3) * 8;

    const float* Af = (const float*)Aptr;
    const f16*   Ah = (const f16*)Aptr;

    f16x8 sa0, sa1, sb0, sb1;

    auto stage_load = [&](int kt) {
        const int k0 = kt * BK;
        if (CONV_A) {
            const float4* p0 = (const float4*)&Af[(size_t)(m0 + ar0) * K_DIM + k0 + ak0];
            const float4* p1 = (const float4*)&Af[(size_t)(m0 + ar1) * K_DIM + k0 + ak1];
            float4 u0 = p0[0], u1 = p0[1];
            float4 v0 = p1[0], v1 = p1[1];
            sa0[0] = (f16)u0.x; sa0[1] = (f16)u0.y; sa0[2] = (f16)u0.z; sa0[3] = (f16)u0.w;
            sa0[4] = (f16)u1.x; sa0[5] = (f16)u1.y; sa0[6] = (f16)u1.z; sa0[7] = (f16)u1.w;
            sa1[0] = (f16)v0.x; sa1[1] = (f16)v0.y; sa1[2] = (f16)v0.z; sa1[3] = (f16)v0.w;
            sa1[4] = (f16)v1.x; sa1[5] = (f16)v1.y; sa1[6] = (f16)v1.z; sa1[7] = (f16)v1.w;
        } else {
            sa0 = *(const f16x8*)&Ah[(size_t)(m0 + ar0) * K_DIM + k0 + ak0];
            sa1 = *(const f16x8*)&Ah[(size_t)(m0 + ar1) * K_DIM + k0 + ak1];
        }
        sb0 = *(const f16x8*)&B[(size_t)(n0 + ar0) * K_DIM + k0 + ak0];
        sb1 = *(const f16x8*)&B[(size_t)(n0 + ar1) * K_DIM + k0 + ak1];
    };

    auto stage_write = [&](int buf) {
        *(f16x8*)&As[buf][ar0 * BK + ak0] = sa0;
        *(f16x8*)&As[buf][ar1 * BK + ak1] = sa1;
        *(f16x8*)&Bs[buf][ar0 * BK + ak0] = sb0;
        *(f16x8*)&Bs[buf][ar1 * BK + ak1] = sb1;
    };

    f32x4 acc[4][4] = {};

    stage_load(0);
    stage_write(0);
    __syncthreads();

    for (int t = 0; t < NT; ++t) {
        const int cur = t & 1;
        if (t + 1 < NT) stage_load(t + 1);   // issue early: latency hides under MFMA

        f16x8 afr[4], bfr[4];
#pragma unroll
        for (int i = 0; i < 4; ++i)
            afr[i] = *(const f16x8*)&As[cur][(wm + i * 16 + (lane & 15)) * BK + (lane >> 4) * 8];
#pragma unroll
        for (int j = 0; j < 4; ++j)
            bfr[j] = *(const f16x8*)&Bs[cur][(wn + j * 16 + (lane & 15)) * BK + (lane >> 4) * 8];

#pragma unroll
        for (int i = 0; i < 4; ++i)
#pragma unroll
            for (int j = 0; j < 4; ++j)
                acc[i][j] = __builtin_amdgcn_mfma_f32_16x16x32_f16(afr[i], bfr[j], acc[i][j], 0, 0, 0);

        if (t + 1 < NT) stage_write(cur ^ 1);
        __syncthreads();
    }

    // ---- epilogue ----
    // C/D fragment layout (16x16): col = lane&15, row = (lane>>4)*4 + reg
    const int col_in = lane & 15;
    const int row_hi = (lane >> 4) * 4;

    if (QUANTUM) {
        // meas = cumprod(cos(q)) along f within 8-wide groups.
        // group position = lane&7 (all f-tile bases are multiples of 8).
        f16* Ch = (f16*)Cptr;
#pragma unroll
        for (int i = 0; i < 4; ++i) {
#pragma unroll
            for (int j = 0; j < 4; ++j) {
#pragma unroll
                for (int r = 0; r < 4; ++r) {
                    float v = __cosf(acc[i][j][r]);
                    // Kogge-Stone inclusive prefix product over 8-lane segment
#pragma unroll
                    for (int d = 1; d < 8; d <<= 1) {
                        float tsh = __shfl(v, lane - d, 64);
                        if ((lane & 7) >= d) v *= tsh;
                    }
                    const int row = m0 + wm + i * 16 + row_hi + r;
                    const int col = n0 + wn + j * 16 + col_in;
                    Ch[(size_t)row * K_DIM + col] = (f16)v;
                }
            }
        }
    } else {
        float* Cf = (float*)Cptr;
#pragma unroll
        for (int i = 0; i < 4; ++i) {
#pragma unroll
            for (int j = 0; j < 4; ++j) {
#pragma unroll
                for (int r = 0; r < 4; ++r) {
                    const int row = m0 + wm + i * 16 + row_hi + r;
                    const int col = n0 + wn + j * 16 + col_in;
                    Cf[(size_t)row * K_DIM + col] = acc[i][j][r];
                }
            }
        }
    }
}

// ---------------------------------------------------------------------------
extern "C" void kernel_launch(void* const* d_in, const int* in_sizes, int n_in,
                              void* d_out, int out_size, void* d_ws, size_t ws_size,
                              hipStream_t stream) {
    const float* x  = (const float*)d_in[0];
    const float* Wq = (const float*)d_in[1];
    // d_in[2] = Wk, d_in[3] = Wv: dead compute in the reference, never used
    const float* Wo = (const float*)d_in[4];

    const int M = in_sizes[0] / K_DIM;   // B*S = 32768

    char* ws = (char*)d_ws;
    f16* meas = (f16*)ws;                                    // M*512 fp16 (32 MB)
    f16* wq_h = (f16*)(ws + (size_t)M * K_DIM * sizeof(f16));
    f16* wo_h = wq_h + 512 * 512;

    // 1) convert weights to fp16
    convert_w_kernel<<<512, 256, 0, stream>>>(Wq, Wo, wq_h, wo_h);

    // 2) q = x @ Wq^T  -> meas = cumprod(cos(q)) (fp16)
    dim3 grid(K_DIM / BN, M / BM);   // (4, 256)
    gemm_kernel<true, true><<<grid, 256, 0, stream>>>(x, wq_h, meas);

    // 3) out = meas @ Wo^T (fp32)
    gemm_kernel<false, false><<<grid, 256, 0, stream>>>(meas, wo_h, d_out);
}

// Round 2
// 78.335 us; speedup vs baseline: 1.2078x; 1.2078x over previous
//
#include <hip/hip_runtime.h>

typedef _Float16 f16;
typedef f16  f16x8 __attribute__((ext_vector_type(8)));
typedef float f32x4 __attribute__((ext_vector_type(4)));

#define K_DIM 512
#define BM 128
#define BN 128
#define BK 32
#define BKP 40            /* padded LDS leading dim: 80 B rows -> 20-bank stride, ~2-way max */
#define NT (K_DIM / BK)   /* 16 K-steps */
#define N_TILES (K_DIM / BN)  /* 4 */

// ---------------------------------------------------------------------------
// Weight convert: Wq, Wo (fp32 [512][512]) -> fp16 copies in workspace
// ---------------------------------------------------------------------------
__global__ void convert_w_kernel(const float* __restrict__ wq,
                                 const float* __restrict__ wo,
                                 f16* __restrict__ wq_h,
                                 f16* __restrict__ wo_h) {
    int i = blockIdx.x * blockDim.x + threadIdx.x;   // each thread: one float4
    const int n4 = (512 * 512) / 4;
    const float4* src;
    f16* dst;
    if (i < n4) { src = (const float4*)wq; dst = wq_h; }
    else        { src = (const float4*)wo; dst = wo_h; i -= n4; }
    float4 v = src[i];
    f16* p = dst + (size_t)i * 4;
    p[0] = (f16)v.x; p[1] = (f16)v.y; p[2] = (f16)v.z; p[3] = (f16)v.w;
}

// ---------------------------------------------------------------------------
// GEMM: C[M x 512] = A[M x 512] * B^T   (B stored [N=512][K=512] row-major)
//  CONV_A:  A is fp32, convert to fp16 while staging (GEMM1: A = x)
//  QUANTUM: epilogue = cumprod(cos(.)) over 8-wide groups along N, fp16 store
//           else plain fp32 store (GEMM2)
// 256 threads = 4 waves (2x2), wave tile 64x64, mfma_f32_16x16x32_f16
// 1D grid, XCD-chunked swizzle, n-index fastest (same-m quads share an XCD L2)
// ---------------------------------------------------------------------------
template <bool CONV_A, bool QUANTUM>
__global__ __launch_bounds__(256, 4)
void gemm_kernel(const void* __restrict__ Aptr,
                 const f16* __restrict__ B,
                 void* __restrict__ Cptr) {
    __shared__ f16 As[2][BM * BKP];
    __shared__ f16 Bs[2][BN * BKP];

    const int tid  = threadIdx.x;
    const int lane = tid & 63;
    const int wave = tid >> 6;
    const int wm = (wave >> 1) * 64;   // wave row offset in tile
    const int wn = (wave & 1) * 64;    // wave col offset in tile

    // XCD-chunked bijective swizzle: bid%8 == XCD (round-robin dispatch).
    // chunk = gridDim.x/8 consecutive swizzled ids per XCD; n fastest within.
    const int bid = blockIdx.x;
    const int chunk = gridDim.x >> 3;
    const int swz = (bid & 7) * chunk + (bid >> 3);
    const int m0 = (swz >> 2) * BM;          // N_TILES == 4
    const int n0 = (swz & 3) * BN;

    // staging: 128 rows x 4 k-groups (8 f16 each); 256 threads, 2 groups each
    const int ar0 = tid >> 2,         ak0 = (tid & 3) * 8;
    const int ar1 = (tid + 256) >> 2, ak1 = ((tid + 256) & 3) * 8;

    const float* Af = (const float*)Aptr;
    const f16*   Ah = (const f16*)Aptr;

    f16x8 sa0, sa1, sb0, sb1;

    auto stage_load = [&](int kt) {
        const int k0 = kt * BK;
        if (CONV_A) {
            const float4* p0 = (const float4*)&Af[(size_t)(m0 + ar0) * K_DIM + k0 + ak0];
            const float4* p1 = (const float4*)&Af[(size_t)(m0 + ar1) * K_DIM + k0 + ak1];
            float4 u0 = p0[0], u1 = p0[1];
            float4 v0 = p1[0], v1 = p1[1];
            sa0[0] = (f16)u0.x; sa0[1] = (f16)u0.y; sa0[2] = (f16)u0.z; sa0[3] = (f16)u0.w;
            sa0[4] = (f16)u1.x; sa0[5] = (f16)u1.y; sa0[6] = (f16)u1.z; sa0[7] = (f16)u1.w;
            sa1[0] = (f16)v0.x; sa1[1] = (f16)v0.y; sa1[2] = (f16)v0.z; sa1[3] = (f16)v0.w;
            sa1[4] = (f16)v1.x; sa1[5] = (f16)v1.y; sa1[6] = (f16)v1.z; sa1[7] = (f16)v1.w;
        } else {
            sa0 = *(const f16x8*)&Ah[(size_t)(m0 + ar0) * K_DIM + k0 + ak0];
            sa1 = *(const f16x8*)&Ah[(size_t)(m0 + ar1) * K_DIM + k0 + ak1];
        }
        sb0 = *(const f16x8*)&B[(size_t)(n0 + ar0) * K_DIM + k0 + ak0];
        sb1 = *(const f16x8*)&B[(size_t)(n0 + ar1) * K_DIM + k0 + ak1];
    };

    auto stage_write = [&](int buf) {
        *(f16x8*)&As[buf][ar0 * BKP + ak0] = sa0;
        *(f16x8*)&As[buf][ar1 * BKP + ak1] = sa1;
        *(f16x8*)&Bs[buf][ar0 * BKP + ak0] = sb0;
        *(f16x8*)&Bs[buf][ar1 * BKP + ak1] = sb1;
    };

    f32x4 acc[4][4] = {};

    stage_load(0);
    stage_write(0);
    __syncthreads();

    for (int t = 0; t < NT; ++t) {
        const int cur = t & 1;
        if (t + 1 < NT) stage_load(t + 1);   // T14: issue early, hide under MFMA

        f16x8 afr[4], bfr[4];
#pragma unroll
        for (int i = 0; i < 4; ++i)
            afr[i] = *(const f16x8*)&As[cur][(wm + i * 16 + (lane & 15)) * BKP + (lane >> 4) * 8];
#pragma unroll
        for (int j = 0; j < 4; ++j)
            bfr[j] = *(const f16x8*)&Bs[cur][(wn + j * 16 + (lane & 15)) * BKP + (lane >> 4) * 8];

#pragma unroll
        for (int i = 0; i < 4; ++i)
#pragma unroll
            for (int j = 0; j < 4; ++j)
                acc[i][j] = __builtin_amdgcn_mfma_f32_16x16x32_f16(afr[i], bfr[j], acc[i][j], 0, 0, 0);

        if (t + 1 < NT) stage_write(cur ^ 1);  // write late (after vmcnt drain)
        __syncthreads();
    }

    // ---- epilogue ----
    // C/D fragment layout (16x16): col = lane&15, row = (lane>>4)*4 + reg
    const int col_in = lane & 15;
    const int row_hi = (lane >> 4) * 4;

    if (QUANTUM) {
        // meas = cumprod(cos(q)) along f within 8-wide groups (group pos = lane&7)
        f16* Ch = (f16*)Cptr;
#pragma unroll
        for (int i = 0; i < 4; ++i) {
#pragma unroll
            for (int j = 0; j < 4; ++j) {
#pragma unroll
                for (int r = 0; r < 4; ++r) {
                    float v = __cosf(acc[i][j][r]);
#pragma unroll
                    for (int d = 1; d < 8; d <<= 1) {  // Kogge-Stone prefix product
                        float tsh = __shfl(v, lane - d, 64);
                        if ((lane & 7) >= d) v *= tsh;
                    }
                    const int row = m0 + wm + i * 16 + row_hi + r;
                    const int col = n0 + wn + j * 16 + col_in;
                    Ch[(size_t)row * K_DIM + col] = (f16)v;
                }
            }
        }
    } else {
        float* Cf = (float*)Cptr;
#pragma unroll
        for (int i = 0; i < 4; ++i) {
#pragma unroll
            for (int j = 0; j < 4; ++j) {
#pragma unroll
                for (int r = 0; r < 4; ++r) {
                    const int row = m0 + wm + i * 16 + row_hi + r;
                    const int col = n0 + wn + j * 16 + col_in;
                    Cf[(size_t)row * K_DIM + col] = acc[i][j][r];
                }
            }
        }
    }
}

// ---------------------------------------------------------------------------
extern "C" void kernel_launch(void* const* d_in, const int* in_sizes, int n_in,
                              void* d_out, int out_size, void* d_ws, size_t ws_size,
                              hipStream_t stream) {
    const float* x  = (const float*)d_in[0];
    const float* Wq = (const float*)d_in[1];
    // d_in[2] = Wk, d_in[3] = Wv: dead compute in the reference, never used
    const float* Wo = (const float*)d_in[4];

    const int M = in_sizes[0] / K_DIM;   // B*S = 32768

    char* ws = (char*)d_ws;
    f16* meas = (f16*)ws;                                    // M*512 fp16 (32 MB)
    f16* wq_h = (f16*)(ws + (size_t)M * K_DIM * sizeof(f16));
    f16* wo_h = wq_h + 512 * 512;

    convert_w_kernel<<<512, 256, 0, stream>>>(Wq, Wo, wq_h, wo_h);

    const int nblk = (M / BM) * N_TILES;   // 1024, divisible by 8
    gemm_kernel<true, true><<<nblk, 256, 0, stream>>>(x, wq_h, meas);
    gemm_kernel<false, false><<<nblk, 256, 0, stream>>>(meas, wo_h, d_out);
}

// Round 3
// 75.694 us; speedup vs baseline: 1.2499x; 1.0349x over previous
//
#include <hip/hip_runtime.h>

typedef _Float16 f16;
typedef f16   f16x8 __attribute__((ext_vector_type(8)));
typedef float f32x4 __attribute__((ext_vector_type(4)));

#define K_DIM 512
#define BM 128
#define BN 128
#define BK 32
#define NT (K_DIM / BK)       /* 16 K-steps */
#define N_TILES (K_DIM / BN)  /* 4 */

// direct global->LDS async copy, 16B per lane (dst = wave-uniform base + lane*16)
__device__ __forceinline__ void load_lds16(const void* g, void* l) {
    __builtin_amdgcn_global_load_lds(
        (const __attribute__((address_space(1))) unsigned int*)g,
        (__attribute__((address_space(3))) unsigned int*)l,
        16, 0, 0);
}

// ---------------------------------------------------------------------------
// Weight convert: Wq, Wo (fp32 [512][512]) -> fp16 copies in workspace
// ---------------------------------------------------------------------------
__global__ void convert_w_kernel(const float* __restrict__ wq,
                                 const float* __restrict__ wo,
                                 f16* __restrict__ wq_h,
                                 f16* __restrict__ wo_h) {
    int i = blockIdx.x * blockDim.x + threadIdx.x;
    const int n4 = (512 * 512) / 4;
    const float4* src;
    f16* dst;
    if (i < n4) { src = (const float4*)wq; dst = wq_h; }
    else        { src = (const float4*)wo; dst = wo_h; i -= n4; }
    float4 v = src[i];
    f16* p = dst + (size_t)i * 4;
    p[0] = (f16)v.x; p[1] = (f16)v.y; p[2] = (f16)v.z; p[3] = (f16)v.w;
}

// ---------------------------------------------------------------------------
// GEMM: C[M x 512] = A[M x 512] * B^T   (B stored [N=512][K=512] f16 row-major)
//  CONV_A:  A is fp32 -> staged to LDS as fp32 via global_load_lds, cvt in reg
//  QUANTUM: epilogue = cumprod(cos(.)) over 8-wide groups along N, f16 store
// 256 threads = 4 waves (2x2), wave tile 64x64, mfma_f32_16x16x32_f16
// 2-phase pipeline: STAGE(next) via global_load_lds issued first, then
// ds_read cur + MFMA, then one __syncthreads (vmcnt0+lgkmcnt0+barrier) / step.
// ---------------------------------------------------------------------------
template <bool CONV_A, bool QUANTUM>
__global__ __launch_bounds__(256, CONV_A ? 3 : 4)
void gemm_kernel(const void* __restrict__ Aptr,
                 const f16* __restrict__ B,
                 void* __restrict__ Cptr) {
    constexpr int ABYTES = (CONV_A ? 4 : 2) * BM * BK;   // 16KB fp32 / 8KB f16
    constexpr int BBYTES = 2 * BN * BK;                  // 8KB
    __shared__ __align__(16) char smem[2][ABYTES + BBYTES];

    const int tid  = threadIdx.x;
    const int lane = tid & 63;
    const int wave = tid >> 6;
    const int wm = (wave >> 1) * 64;
    const int wn = (wave & 1) * 64;

    // XCD-chunked bijective swizzle (gridDim.x divisible by 8), n fastest
    const int bid = blockIdx.x;
    const int chunk = gridDim.x >> 3;
    const int swz = (bid & 7) * chunk + (bid >> 3);
    const int m0 = (swz >> 2) * BM;          // N_TILES == 4
    const int n0 = (swz & 3) * BN;

    const float* Af = (const float*)Aptr;
    const f16*   Ah = (const f16*)Aptr;

    // stage one K-tile into buffer `buf` (async, no regs)
    auto stage = [&](int buf, int kt) {
        const int k0 = kt * BK;
        char* as = smem[buf];
        char* bs = smem[buf] + ABYTES;
        if (CONV_A) {
            // A fp32 [128][32]: 16KB = 16 x 1KB chunks, 4 per wave
            // granule G (16B): row = G>>3, f32 col = (G&7)*4
#pragma unroll
            for (int c = 0; c < 4; ++c) {
                const int ch = wave * 4 + c;
                const int G = ch * 64 + lane;
                const float* src = Af + (size_t)(m0 + (G >> 3)) * K_DIM + k0 + (G & 7) * 4;
                load_lds16(src, as + ch * 1024);
            }
        } else {
            // A f16 [128][32]: 8KB = 8 chunks, 2 per wave
            // granule G: row = G>>2, f16 col = (G&3)*8
#pragma unroll
            for (int c = 0; c < 2; ++c) {
                const int ch = wave * 2 + c;
                const int G = ch * 64 + lane;
                const f16* src = Ah + (size_t)(m0 + (G >> 2)) * K_DIM + k0 + (G & 3) * 8;
                load_lds16(src, as + ch * 1024);
            }
        }
        // B f16 [128][32]: 8KB = 8 chunks, 2 per wave
#pragma unroll
        for (int c = 0; c < 2; ++c) {
            const int ch = wave * 2 + c;
            const int G = ch * 64 + lane;
            const f16* src = B + (size_t)(n0 + (G >> 2)) * K_DIM + k0 + (G & 3) * 8;
            load_lds16(src, bs + ch * 1024);
        }
    };

    f32x4 acc[4][4] = {};

    const int fr = lane & 15;        // fragment row/col within 16
    const int kq = lane >> 4;        // k-quarter (8 elems)

    stage(0, 0);
    __syncthreads();

    for (int t = 0; t < NT; ++t) {
        const int cur = t & 1;
        if (t + 1 < NT) stage(cur ^ 1, t + 1);   // issue first; drains at syncthreads

        const char* as = smem[cur];
        const char* bs = smem[cur] + ABYTES;

        f16x8 afr[4], bfr[4];
        if (CONV_A) {
            const float* af = (const float*)as;
#pragma unroll
            for (int i = 0; i < 4; ++i) {
                const int off = (wm + i * 16 + fr) * BK + kq * 8;
                f32x4 a0 = *(const f32x4*)&af[off];
                f32x4 a1 = *(const f32x4*)&af[off + 4];
#pragma unroll
                for (int r = 0; r < 4; ++r) {
                    afr[i][r]     = (f16)a0[r];
                    afr[i][4 + r] = (f16)a1[r];
                }
            }
        } else {
            const f16* af = (const f16*)as;
#pragma unroll
            for (int i = 0; i < 4; ++i)
                afr[i] = *(const f16x8*)&af[(wm + i * 16 + fr) * BK + kq * 8];
        }
        const f16* bf = (const f16*)bs;
#pragma unroll
        for (int j = 0; j < 4; ++j)
            bfr[j] = *(const f16x8*)&bf[(wn + j * 16 + fr) * BK + kq * 8];

#pragma unroll
        for (int i = 0; i < 4; ++i)
#pragma unroll
            for (int j = 0; j < 4; ++j)
                acc[i][j] = __builtin_amdgcn_mfma_f32_16x16x32_f16(afr[i], bfr[j], acc[i][j], 0, 0, 0);

        __syncthreads();   // vmcnt(0)+lgkmcnt(0)+barrier: next buffer staged & visible
    }

    // ---- epilogue ----
    // C/D layout (16x16): col = lane&15, row = (lane>>4)*4 + reg
    const int col_in = fr;
    const int row_hi = kq * 4;

    if (QUANTUM) {
        f16* Ch = (f16*)Cptr;
#pragma unroll
        for (int i = 0; i < 4; ++i) {
#pragma unroll
            for (int j = 0; j < 4; ++j) {
#pragma unroll
                for (int r = 0; r < 4; ++r) {
                    float v = __cosf(acc[i][j][r]);
#pragma unroll
                    for (int d = 1; d < 8; d <<= 1) {   // prefix product over 8-lane seg
                        float tsh = __shfl(v, lane - d, 64);
                        if ((lane & 7) >= d) v *= tsh;
                    }
                    const int row = m0 + wm + i * 16 + row_hi + r;
                    const int col = n0 + wn + j * 16 + col_in;
                    Ch[(size_t)row * K_DIM + col] = (f16)v;
                }
            }
        }
    } else {
        float* Cf = (float*)Cptr;
#pragma unroll
        for (int i = 0; i < 4; ++i) {
#pragma unroll
            for (int j = 0; j < 4; ++j) {
#pragma unroll
                for (int r = 0; r < 4; ++r) {
                    const int row = m0 + wm + i * 16 + row_hi + r;
                    const int col = n0 + wn + j * 16 + col_in;
                    Cf[(size_t)row * K_DIM + col] = acc[i][j][r];
                }
            }
        }
    }
}

// ---------------------------------------------------------------------------
extern "C" void kernel_launch(void* const* d_in, const int* in_sizes, int n_in,
                              void* d_out, int out_size, void* d_ws, size_t ws_size,
                              hipStream_t stream) {
    const float* x  = (const float*)d_in[0];
    const float* Wq = (const float*)d_in[1];
    // d_in[2]=Wk, d_in[3]=Wv: dead compute in the reference
    const float* Wo = (const float*)d_in[4];

    const int M = in_sizes[0] / K_DIM;   // 32768

    char* ws = (char*)d_ws;
    f16* meas = (f16*)ws;                                    // M*512 f16 (32 MB)
    f16* wq_h = (f16*)(ws + (size_t)M * K_DIM * sizeof(f16));
    f16* wo_h = wq_h + 512 * 512;

    convert_w_kernel<<<512, 256, 0, stream>>>(Wq, Wo, wq_h, wo_h);

    const int nblk = (M / BM) * N_TILES;   // 1024
    gemm_kernel<true, true><<<nblk, 256, 0, stream>>>(x, wq_h, meas);
    gemm_kernel<false, false><<<nblk, 256, 0, stream>>>(meas, wo_h, d_out);
}